// Round 1
// baseline (580.618 us; speedup 1.0000x reference)
//
#include <hip/hip_runtime.h>
#include <math.h>

#define BATCH 16
#define T0 64000
#define T1 32000
#define T2 16000
#define T3 8000
#define P1 32008   // padded row length for y1 (4 zeros each side)
#define P2 16008   // padded row length for y2

// ---------------- conv1: audio (B,1,64000) -> y1p (B,32,P1), stride 2, k=9, relu
__global__ __launch_bounds__(256) void conv1_k(const float* __restrict__ audio,
                                               const float* __restrict__ w1,
                                               const float* __restrict__ b1,
                                               float* __restrict__ y1p) {
    int p = blockIdx.x * 256 + threadIdx.x;   // padded output position [0, P1)
    if (p >= P1) return;
    int b = blockIdx.y;
    int t = p - 4;
    if (t < 0 || t >= T1) {
        #pragma unroll 4
        for (int c = 0; c < 32; ++c) y1p[(size_t)(b*32 + c)*P1 + p] = 0.f;
        return;
    }
    const float* ar = audio + (size_t)b * T0;
    float x[9];
    #pragma unroll
    for (int k = 0; k < 9; ++k) {
        int idx = 2*t + k - 4;
        x[k] = (idx >= 0 && idx < T0) ? ar[idx] : 0.f;
    }
    #pragma unroll 4
    for (int c = 0; c < 32; ++c) {
        float acc = b1[c];
        #pragma unroll
        for (int k = 0; k < 9; ++k) acc = fmaf(x[k], w1[c*9 + k], acc);
        y1p[(size_t)(b*32 + c)*P1 + p] = fmaxf(acc, 0.f);
    }
}

// ---------------- conv2: y1p (B,32,P1) -> y2p (B,64,P2), stride 2, k=9, relu
// thread = one output time position, 8 out-channels register-blocked
__global__ __launch_bounds__(256) void conv2_k(const float* __restrict__ y1p,
                                               const float* __restrict__ w2,
                                               const float* __restrict__ b2,
                                               float* __restrict__ y2p) {
    int p = blockIdx.x * 256 + threadIdx.x;   // padded output pos [0, P2)
    if (p >= P2) return;
    int b  = blockIdx.z;
    int o0 = blockIdx.y * 8;
    int t  = p - 4;
    if (t < 0 || t >= T2) {
        #pragma unroll
        for (int j = 0; j < 8; ++j) y2p[(size_t)(b*64 + o0 + j)*P2 + p] = 0.f;
        return;
    }
    float acc[8];
    #pragma unroll
    for (int j = 0; j < 8; ++j) acc[j] = b2[o0 + j];
    const float* xb = y1p + (size_t)(b*32)*P1 + 2*t;  // padded: input idx = 2t+k
    for (int i = 0; i < 32; ++i) {
        const float* xr = xb + (size_t)i * P1;        // 8B-aligned (P1 even, 2t even)
        float2 a0 = *(const float2*)(xr + 0);
        float2 a1 = *(const float2*)(xr + 2);
        float2 a2 = *(const float2*)(xr + 4);
        float2 a3 = *(const float2*)(xr + 6);
        float  x8 = xr[8];
        float x[9] = {a0.x, a0.y, a1.x, a1.y, a2.x, a2.y, a3.x, a3.y, x8};
        const float* wr = w2 + (size_t)(o0*32 + i) * 9;   // uniform -> s_load
        #pragma unroll
        for (int j = 0; j < 8; ++j) {
            #pragma unroll
            for (int k = 0; k < 9; ++k)
                acc[j] = fmaf(x[k], wr[j*288 + k], acc[j]);
        }
    }
    #pragma unroll
    for (int j = 0; j < 8; ++j)
        y2p[(size_t)(b*64 + o0 + j)*P2 + p] = fmaxf(acc[j], 0.f);
}

// ---------------- conv3 + mean-pool: y2p (B,64,P2) -> pooled_sum (B,128)
__global__ __launch_bounds__(256) void conv3_pool_k(const float* __restrict__ y2p,
                                                    const float* __restrict__ w3,
                                                    const float* __restrict__ b3,
                                                    float* __restrict__ pooled) {
    __shared__ float red[8][256];
    int tid = threadIdx.x;
    int t   = blockIdx.x * 256 + tid;
    int b   = blockIdx.z;
    int o0  = blockIdx.y * 8;
    float acc[8];
    #pragma unroll
    for (int j = 0; j < 8; ++j) acc[j] = 0.f;
    if (t < T3) {
        #pragma unroll
        for (int j = 0; j < 8; ++j) acc[j] = b3[o0 + j];
        const float* xb = y2p + (size_t)(b*64)*P2 + 2*t;
        for (int i = 0; i < 64; ++i) {
            const float* xr = xb + (size_t)i * P2;
            float2 a0 = *(const float2*)(xr + 0);
            float2 a1 = *(const float2*)(xr + 2);
            float2 a2 = *(const float2*)(xr + 4);
            float2 a3 = *(const float2*)(xr + 6);
            float  x8 = xr[8];
            float x[9] = {a0.x, a0.y, a1.x, a1.y, a2.x, a2.y, a3.x, a3.y, x8};
            const float* wr = w3 + (size_t)(o0*64 + i) * 9;   // uniform -> s_load
            #pragma unroll
            for (int j = 0; j < 8; ++j) {
                #pragma unroll
                for (int k = 0; k < 9; ++k)
                    acc[j] = fmaf(x[k], wr[j*576 + k], acc[j]);
            }
        }
        #pragma unroll
        for (int j = 0; j < 8; ++j) acc[j] = fmaxf(acc[j], 0.f);
    }
    #pragma unroll
    for (int j = 0; j < 8; ++j) red[j][tid] = acc[j];
    __syncthreads();
    for (int s = 128; s > 0; s >>= 1) {
        if (tid < s) {
            #pragma unroll
            for (int j = 0; j < 8; ++j) red[j][tid] += red[j][tid + s];
        }
        __syncthreads();
    }
    if (tid < 8) atomicAdd(&pooled[b*128 + o0 + tid], red[tid][0]);
}

// ---------------- linear head: pooled_sum/8000 @ wl.T + bl -> amps (normalized), nmag
__global__ __launch_bounds__(128) void feats_k(const float* __restrict__ pooled,
                                               const float* __restrict__ wl,
                                               const float* __restrict__ bl,
                                               float* __restrict__ amps,
                                               float* __restrict__ nmag) {
    int b = blockIdx.x;
    int o = threadIdx.x;
    __shared__ float pl[128];
    __shared__ float sh[128];
    pl[o] = pooled[b*128 + o] * (1.0f / 8000.0f);
    __syncthreads();
    float acc = bl[o];
    #pragma unroll 8
    for (int i = 0; i < 128; ++i) acc = fmaf(pl[i], wl[o*128 + i], acc);
    sh[o] = (o < 64) ? fmaxf(acc, 0.f) : 0.f;
    __syncthreads();
    for (int s = 64; s > 0; s >>= 1) {
        if (o < s) sh[o] += sh[o + s];
        __syncthreads();
    }
    float denom = sh[0] + 1e-6f;
    if (o < 64) amps[b*64 + o] = fmaxf(acc, 0.f) / denom;
    else        nmag[b*64 + (o - 64)] = acc;
}

// ---------------- synthesis: harmonics + shaped noise -> out (B,64000)
__global__ __launch_bounds__(256) void synth_k(const float* __restrict__ f0,
                                               const float* __restrict__ wn,
                                               const float* __restrict__ amps,
                                               const float* __restrict__ nmag,
                                               float* __restrict__ out) {
    int t = blockIdx.x * 256 + threadIdx.x;
    int b = blockIdx.y;
    __shared__ float sa[64];
    if (threadIdx.x < 64) sa[threadIdx.x] = amps[b*64 + threadIdx.x];
    __syncthreads();
    float f0v = f0[(size_t)b*T0 + t];
    // u = f0 * t_sec, t_sec = t * 4/63999 (linspace incl. endpoint). frac in double,
    // so per-harmonic frac(h*uf) is accurate (phase >> 2pi would lose 0.06 rad in fp32).
    double u  = (double)f0v * ((double)t * (4.0 / 63999.0));
    float  uf = (float)(u - floor(u));
    float acc = 0.f;
    #pragma unroll
    for (int h = 1; h <= 64; ++h) {
        float x = uf * (float)h;
        x = x - floorf(x);                       // v_fract
        acc = fmaf(sa[h-1], __builtin_amdgcn_sinf(x), acc);  // sin(2*pi*x)
    }
    float nm = nmag[b*64 + (t / 1000)];
    out[(size_t)b*T0 + t] = acc + wn[(size_t)b*T0 + t] * nm;
}

extern "C" void kernel_launch(void* const* d_in, const int* in_sizes, int n_in,
                              void* d_out, int out_size, void* d_ws, size_t ws_size,
                              hipStream_t stream) {
    const float* audio = (const float*)d_in[0];
    const float* f0    = (const float*)d_in[1];
    const float* wn    = (const float*)d_in[2];
    const float* w1    = (const float*)d_in[3];
    const float* b1    = (const float*)d_in[4];
    const float* w2    = (const float*)d_in[5];
    const float* b2    = (const float*)d_in[6];
    const float* w3    = (const float*)d_in[7];
    const float* b3    = (const float*)d_in[8];
    const float* wl    = (const float*)d_in[9];
    const float* bl    = (const float*)d_in[10];
    float* out = (float*)d_out;

    float* ws     = (float*)d_ws;
    float* y1p    = ws;                                   // B*32*P1
    float* y2p    = y1p + (size_t)BATCH * 32 * P1;        // B*64*P2
    float* pooled = y2p + (size_t)BATCH * 64 * P2;        // B*128 (sums)
    float* amps   = pooled + BATCH * 128;                 // B*64
    float* nmag   = amps + BATCH * 64;                    // B*64

    hipMemsetAsync(pooled, 0, BATCH * 128 * sizeof(float), stream);

    conv1_k<<<dim3((P1 + 255) / 256, BATCH), 256, 0, stream>>>(audio, w1, b1, y1p);
    conv2_k<<<dim3((P2 + 255) / 256, 8, BATCH), 256, 0, stream>>>(y1p, w2, b2, y2p);
    conv3_pool_k<<<dim3((T3 + 255) / 256, 16, BATCH), 256, 0, stream>>>(y2p, w3, b3, pooled);
    feats_k<<<dim3(BATCH), 128, 0, stream>>>(pooled, wl, bl, amps, nmag);
    synth_k<<<dim3(T0 / 256, BATCH), 256, 0, stream>>>(f0, wn, amps, nmag, out);
}

// Round 2
// 400.663 us; speedup vs baseline: 1.4491x; 1.4491x over previous
//
#include <hip/hip_runtime.h>
#include <math.h>

#define BATCH 16
#define T0 64000
#define T1 32000
#define T2 16000
#define T3 8000
#define P1 32008   // padded row length for y1 (4 zeros each side)
#define P2 16008   // padded row length for y2

// ---------------- conv1: audio (B,1,64000) -> y1p (B,32,P1), stride 2, k=9, relu
__global__ __launch_bounds__(256) void conv1_k(const float* __restrict__ audio,
                                               const float* __restrict__ w1,
                                               const float* __restrict__ b1,
                                               float* __restrict__ y1p) {
    int p = blockIdx.x * 256 + threadIdx.x;   // padded output position [0, P1)
    if (p >= P1) return;
    int b = blockIdx.y;
    int t = p - 4;
    if (t < 0 || t >= T1) {
        #pragma unroll 4
        for (int c = 0; c < 32; ++c) y1p[(size_t)(b*32 + c)*P1 + p] = 0.f;
        return;
    }
    const float* ar = audio + (size_t)b * T0;
    float x[9];
    #pragma unroll
    for (int k = 0; k < 9; ++k) {
        int idx = 2*t + k - 4;
        x[k] = (idx >= 0 && idx < T0) ? ar[idx] : 0.f;
    }
    #pragma unroll 4
    for (int c = 0; c < 32; ++c) {
        float acc = b1[c];
        #pragma unroll
        for (int k = 0; k < 9; ++k) acc = fmaf(x[k], w1[c*9 + k], acc);
        y1p[(size_t)(b*32 + c)*P1 + p] = fmaxf(acc, 0.f);
    }
}

// ---------------- zero the 8 pad columns of y2p (conv2 no longer writes them)
__global__ __launch_bounds__(256) void pad2_k(float* __restrict__ y2p) {
    int idx = blockIdx.x * 256 + threadIdx.x;   // 16*64*8 = 8192
    if (idx >= BATCH * 64 * 8) return;
    int row = idx >> 3, off = idx & 7;
    int p = (off < 4) ? off : (T2 + off);       // 0..3 and 16004..16007
    y2p[(size_t)row * P2 + p] = 0.f;
}

// ---------------- conv2: y1p (B,32,P1) -> y2p (B,64,P2), stride 2, k=9, relu
// thread = 4 consecutive t positions x 8 out-channels (288 FMA per input chan)
__global__ __launch_bounds__(256) void conv2_k(const float* __restrict__ y1p,
                                               const float* __restrict__ w2,
                                               const float* __restrict__ b2,
                                               float* __restrict__ y2p) {
    int t0 = (blockIdx.x * 256 + threadIdx.x) * 4;
    if (t0 >= T2) return;
    int b  = blockIdx.z;
    int o0 = blockIdx.y * 8;
    float acc[8][4];
    #pragma unroll
    for (int j = 0; j < 8; ++j) {
        float bb = b2[o0 + j];
        #pragma unroll
        for (int u = 0; u < 4; ++u) acc[j][u] = bb;
    }
    const float* xb = y1p + (size_t)(b*32)*P1 + 2*t0;   // 2*t0 % 8 == 0 -> 16B aligned
    for (int i = 0; i < 32; ++i) {
        const float* xr = xb + (size_t)i * P1;
        float4 A = *(const float4*)(xr + 0);
        float4 Bv = *(const float4*)(xr + 4);
        float4 C = *(const float4*)(xr + 8);
        float2 D = *(const float2*)(xr + 12);
        float  E = xr[14];
        float x[15] = {A.x,A.y,A.z,A.w, Bv.x,Bv.y,Bv.z,Bv.w, C.x,C.y,C.z,C.w, D.x,D.y, E};
        const float* wr = w2 + (size_t)(o0*32 + i) * 9;   // wave-uniform -> s_load
        #pragma unroll
        for (int j = 0; j < 8; ++j) {
            #pragma unroll
            for (int k = 0; k < 9; ++k) {
                float wv = wr[j*288 + k];
                #pragma unroll
                for (int u = 0; u < 4; ++u)
                    acc[j][u] = fmaf(x[2*u + k], wv, acc[j][u]);
            }
        }
    }
    #pragma unroll
    for (int j = 0; j < 8; ++j) {
        float4 st = { fmaxf(acc[j][0], 0.f), fmaxf(acc[j][1], 0.f),
                      fmaxf(acc[j][2], 0.f), fmaxf(acc[j][3], 0.f) };
        *(float4*)(y2p + (size_t)(b*64 + o0 + j)*P2 + 4 + t0) = st;   // (4+t0)%4==0
    }
}

// ---------------- conv3 + mean-pool: y2p (B,64,P2) -> pooled_sum (B,128)
// thread = 4 consecutive t positions x 8 out-channels, then block reduce
__global__ __launch_bounds__(256) void conv3_pool_k(const float* __restrict__ y2p,
                                                    const float* __restrict__ w3,
                                                    const float* __restrict__ b3,
                                                    float* __restrict__ pooled) {
    __shared__ float red[8][256];
    int tid = threadIdx.x;
    int t0  = (blockIdx.x * 256 + tid) * 4;
    int b   = blockIdx.z;
    int o0  = blockIdx.y * 8;
    float sum[8];
    #pragma unroll
    for (int j = 0; j < 8; ++j) sum[j] = 0.f;
    if (t0 < T3) {                                     // T3 % 4 == 0 -> all 4 valid
        float acc[8][4];
        #pragma unroll
        for (int j = 0; j < 8; ++j) {
            float bb = b3[o0 + j];
            #pragma unroll
            for (int u = 0; u < 4; ++u) acc[j][u] = bb;
        }
        const float* xb = y2p + (size_t)(b*64)*P2 + 2*t0;
        for (int i = 0; i < 64; ++i) {
            const float* xr = xb + (size_t)i * P2;
            float4 A = *(const float4*)(xr + 0);
            float4 Bv = *(const float4*)(xr + 4);
            float4 C = *(const float4*)(xr + 8);
            float2 D = *(const float2*)(xr + 12);
            float  E = xr[14];
            float x[15] = {A.x,A.y,A.z,A.w, Bv.x,Bv.y,Bv.z,Bv.w, C.x,C.y,C.z,C.w, D.x,D.y, E};
            const float* wr = w3 + (size_t)(o0*64 + i) * 9;   // wave-uniform -> s_load
            #pragma unroll
            for (int j = 0; j < 8; ++j) {
                #pragma unroll
                for (int k = 0; k < 9; ++k) {
                    float wv = wr[j*576 + k];
                    #pragma unroll
                    for (int u = 0; u < 4; ++u)
                        acc[j][u] = fmaf(x[2*u + k], wv, acc[j][u]);
                }
            }
        }
        #pragma unroll
        for (int j = 0; j < 8; ++j) {
            #pragma unroll
            for (int u = 0; u < 4; ++u) sum[j] += fmaxf(acc[j][u], 0.f);
        }
    }
    #pragma unroll
    for (int j = 0; j < 8; ++j) red[j][tid] = sum[j];
    __syncthreads();
    for (int s = 128; s > 0; s >>= 1) {
        if (tid < s) {
            #pragma unroll
            for (int j = 0; j < 8; ++j) red[j][tid] += red[j][tid + s];
        }
        __syncthreads();
    }
    if (tid < 8) atomicAdd(&pooled[b*128 + o0 + tid], red[tid][0]);
}

// ---------------- linear head: pooled_sum/8000 @ wl.T + bl -> amps (normalized), nmag
__global__ __launch_bounds__(128) void feats_k(const float* __restrict__ pooled,
                                               const float* __restrict__ wl,
                                               const float* __restrict__ bl,
                                               float* __restrict__ amps,
                                               float* __restrict__ nmag) {
    int b = blockIdx.x;
    int o = threadIdx.x;
    __shared__ float pl[128];
    __shared__ float sh[128];
    pl[o] = pooled[b*128 + o] * (1.0f / 8000.0f);
    __syncthreads();
    float acc = bl[o];
    #pragma unroll 8
    for (int i = 0; i < 128; ++i) acc = fmaf(pl[i], wl[o*128 + i], acc);
    sh[o] = (o < 64) ? fmaxf(acc, 0.f) : 0.f;
    __syncthreads();
    for (int s = 64; s > 0; s >>= 1) {
        if (o < s) sh[o] += sh[o + s];
        __syncthreads();
    }
    float denom = sh[0] + 1e-6f;
    if (o < 64) amps[b*64 + o] = fmaxf(acc, 0.f) / denom;
    else        nmag[b*64 + (o - 64)] = acc;
}

// ---------------- synthesis: harmonics + shaped noise -> out (B,64000)
__global__ __launch_bounds__(256) void synth_k(const float* __restrict__ f0,
                                               const float* __restrict__ wn,
                                               const float* __restrict__ amps,
                                               const float* __restrict__ nmag,
                                               float* __restrict__ out) {
    int t = blockIdx.x * 256 + threadIdx.x;
    int b = blockIdx.y;
    __shared__ float sa[64];
    if (threadIdx.x < 64) sa[threadIdx.x] = amps[b*64 + threadIdx.x];
    __syncthreads();
    float f0v = f0[(size_t)b*T0 + t];
    // u = f0 * t_sec, t_sec = t * 4/63999 (linspace incl. endpoint). frac in double,
    // so per-harmonic frac(h*uf) is accurate (phase >> 2pi would lose 0.06 rad in fp32).
    double u  = (double)f0v * ((double)t * (4.0 / 63999.0));
    float  uf = (float)(u - floor(u));
    float acc = 0.f;
    #pragma unroll
    for (int h = 1; h <= 64; ++h) {
        float x = uf * (float)h;
        x = x - floorf(x);                       // v_fract
        acc = fmaf(sa[h-1], __builtin_amdgcn_sinf(x), acc);  // sin(2*pi*x)
    }
    float nm = nmag[b*64 + (t / 1000)];
    out[(size_t)b*T0 + t] = acc + wn[(size_t)b*T0 + t] * nm;
}

extern "C" void kernel_launch(void* const* d_in, const int* in_sizes, int n_in,
                              void* d_out, int out_size, void* d_ws, size_t ws_size,
                              hipStream_t stream) {
    const float* audio = (const float*)d_in[0];
    const float* f0    = (const float*)d_in[1];
    const float* wn    = (const float*)d_in[2];
    const float* w1    = (const float*)d_in[3];
    const float* b1    = (const float*)d_in[4];
    const float* w2    = (const float*)d_in[5];
    const float* b2    = (const float*)d_in[6];
    const float* w3    = (const float*)d_in[7];
    const float* b3    = (const float*)d_in[8];
    const float* wl    = (const float*)d_in[9];
    const float* bl    = (const float*)d_in[10];
    float* out = (float*)d_out;

    float* ws     = (float*)d_ws;
    float* y1p    = ws;                                   // B*32*P1
    float* y2p    = y1p + (size_t)BATCH * 32 * P1;        // B*64*P2
    float* pooled = y2p + (size_t)BATCH * 64 * P2;        // B*128 (sums)
    float* amps   = pooled + BATCH * 128;                 // B*64
    float* nmag   = amps + BATCH * 64;                    // B*64

    hipMemsetAsync(pooled, 0, BATCH * 128 * sizeof(float), stream);

    conv1_k<<<dim3((P1 + 255) / 256, BATCH), 256, 0, stream>>>(audio, w1, b1, y1p);
    pad2_k<<<dim3((BATCH*64*8 + 255) / 256), 256, 0, stream>>>(y2p);
    conv2_k<<<dim3(16, 8, BATCH), 256, 0, stream>>>(y1p, w2, b2, y2p);
    conv3_pool_k<<<dim3(8, 16, BATCH), 256, 0, stream>>>(y2p, w3, b3, pooled);
    feats_k<<<dim3(BATCH), 128, 0, stream>>>(pooled, wl, bl, amps, nmag);
    synth_k<<<dim3(T0 / 256, BATCH), 256, 0, stream>>>(f0, wn, amps, nmag, out);
}

// Round 3
// 183.080 us; speedup vs baseline: 3.1714x; 2.1885x over previous
//
#include <hip/hip_runtime.h>
#include <hip/hip_bf16.h>
#include <math.h>

typedef unsigned short u16;
typedef __bf16 bf16x8 __attribute__((ext_vector_type(8)));
typedef float  f32x16 __attribute__((ext_vector_type(16)));
typedef u16    u16x8  __attribute__((ext_vector_type(8)));

#define BATCH 16
#define T0 64000
#define T1 32000
#define T2 16000
#define T3 8000
#define P1 32008   // padded rows of y1t (4 zero rows each side)
#define P2 16008   // padded rows of y2t

static __device__ __forceinline__ u16 f2bf(float f) {
    __hip_bfloat16 h = __float2bfloat16(f);
    return *reinterpret_cast<u16*>(&h);
}
static __device__ __forceinline__ float bf2f(u16 u) {
    __hip_bfloat16 h;
    *reinterpret_cast<u16*>(&h) = u;
    return __bfloat162float(h);
}

// ---------------- weight prep: w2 -> a2[9][2][64][32] bf16 (hi,lo), w3 -> a3[9][2][128][64]
__global__ __launch_bounds__(256) void prep_w_k(const float* __restrict__ w2,
                                                const float* __restrict__ w3,
                                                u16* __restrict__ a2,
                                                u16* __restrict__ a3) {
    int idx = blockIdx.x * 256 + threadIdx.x;
    if (idx < 36864) {
        int kk = idx >> 12, rem = idx & 4095;
        int part = rem >> 11, o = (rem >> 5) & 63, i = rem & 31;
        float v = w2[(o * 32 + i) * 9 + kk];
        u16 hv = f2bf(v);
        if (part) hv = f2bf(v - bf2f(hv));
        a2[idx] = hv;
    } else if (idx < 36864 + 147456) {
        int j = idx - 36864;
        int kk = j >> 14, rem = j & 16383;
        int part = rem >> 13, o = (rem >> 6) & 127, i = rem & 63;
        float v = w3[(o * 64 + i) * 9 + kk];
        u16 hv = f2bf(v);
        if (part) hv = f2bf(v - bf2f(hv));
        a3[j] = hv;
    }
}

// ---------------- conv1: audio (B,64000) -> y1t bf16 [b][P1 rows][32 ch], zero pad rows
__global__ __launch_bounds__(256) void conv1_k(const float* __restrict__ audio,
                                               const float* __restrict__ w1,
                                               const float* __restrict__ b1,
                                               u16* __restrict__ y1t) {
    int p = blockIdx.x * 256 + threadIdx.x;
    if (p >= P1) return;
    int b = blockIdx.y;
    u16* dst = y1t + ((size_t)b * P1 + p) * 32;
    int t = p - 4;
    if (t < 0 || t >= T1) {
        u16x8 z; 
        #pragma unroll
        for (int q = 0; q < 8; ++q) z[q] = 0;
        #pragma unroll
        for (int q = 0; q < 4; ++q) *(u16x8*)(dst + q * 8) = z;
        return;
    }
    const float* ar = audio + (size_t)b * T0;
    float x[9];
    #pragma unroll
    for (int k = 0; k < 9; ++k) {
        int idx = 2 * t + k - 4;
        x[k] = (idx >= 0 && idx < T0) ? ar[idx] : 0.f;
    }
    #pragma unroll
    for (int q = 0; q < 4; ++q) {
        u16x8 v;
        #pragma unroll
        for (int j = 0; j < 8; ++j) {
            int c = q * 8 + j;
            float acc = b1[c];
            #pragma unroll
            for (int k = 0; k < 9; ++k) acc = fmaf(x[k], w1[c * 9 + k], acc);
            v[j] = f2bf(fmaxf(acc, 0.f));
        }
        *(u16x8*)(dst + q * 8) = v;
    }
}

// ---------------- zero pad rows of y2t (rows 0..3 and 16004..16007)
__global__ __launch_bounds__(256) void pad_y2_k(u16* __restrict__ y2t) {
    int g = blockIdx.x * 256 + threadIdx.x;    // 1024 granules of 8
    if (g >= 1024) return;
    int b = g >> 6, rem = g & 63;
    int row8 = rem >> 3, c8 = rem & 7;
    int p = (row8 < 4) ? row8 : (16000 + row8);
    u16x8 z;
    #pragma unroll
    for (int q = 0; q < 8; ++q) z[q] = 0;
    *(u16x8*)(y2t + ((size_t)b * P2 + p) * 64 + c8 * 8) = z;
}

// ---------------- conv2 MFMA: y1t -> y2t bf16 [b][P2][64]
// block: 256 thr = 4 waves, M=64 (all o), N=128 t. K = 9 shifts x 2 parts x 32 i.
__global__ __launch_bounds__(256) void conv2_k(const u16* __restrict__ y1t,
                                               const u16* __restrict__ a2,
                                               const float* __restrict__ b2,
                                               u16* __restrict__ y2t) {
    __shared__ u16 sm[15680];              // B: 264 rows x 40 | A(at 10560): 2x64 rows x 40
    const int tid = threadIdx.x;
    const int b = blockIdx.y;
    const int t0 = blockIdx.x * 128;
    const int lane = tid & 63, wv = tid >> 6;
    const int ls = lane >> 5, ln = lane & 31;

    const u16* y1b = y1t + ((size_t)b * P1 + 2 * t0) * 32;
    #pragma unroll
    for (int it = 0; it < 5; ++it) {        // stage B window: 1056 granules
        int g = tid + it * 256;
        if (g < 1056) {
            u16x8 v = *(const u16x8*)(y1b + g * 8);
            *(u16x8*)(sm + (g >> 2) * 40 + (g & 3) * 8) = v;
        }
    }
    #pragma unroll
    for (int it = 0; it < 2; ++it) {        // stage A chunk kk=0 (both parts)
        int g = tid + it * 256;
        u16x8 v = *(const u16x8*)(a2 + g * 8);
        int part = g >> 8, o = (g >> 2) & 63;
        *(u16x8*)(sm + 10560 + (part * 64 + o) * 40 + (g & 3) * 8) = v;
    }
    __syncthreads();

    f32x16 acc[2];
    #pragma unroll
    for (int mi = 0; mi < 2; ++mi)
        #pragma unroll
        for (int q = 0; q < 16; ++q) acc[mi][q] = 0.f;

    for (int kk = 0;;) {
        bf16x8 bf[2];
        #pragma unroll
        for (int step = 0; step < 2; ++step)
            bf[step] = *(const bf16x8*)(sm + (2 * (32 * wv + ln) + kk) * 40 + (2 * step + ls) * 8);
        #pragma unroll
        for (int part = 0; part < 2; ++part)
            #pragma unroll
            for (int step = 0; step < 2; ++step)
                #pragma unroll
                for (int mi = 0; mi < 2; ++mi) {
                    bf16x8 af = *(const bf16x8*)(sm + 10560 + (part * 64 + mi * 32 + ln) * 40 + (2 * step + ls) * 8);
                    acc[mi] = __builtin_amdgcn_mfma_f32_32x32x16_bf16(af, bf[step], acc[mi], 0, 0, 0);
                }
        if (++kk == 9) break;
        __syncthreads();
        #pragma unroll
        for (int it = 0; it < 2; ++it) {
            int g = tid + it * 256;
            u16x8 v = *(const u16x8*)(a2 + kk * 4096 + g * 8);
            int part = g >> 8, o = (g >> 2) & 63;
            *(u16x8*)(sm + 10560 + (part * 64 + o) * 40 + (g & 3) * 8) = v;
        }
        __syncthreads();
    }
    __syncthreads();
    {   // bias+relu, transpose via LDS to [n][o] (rows 72 for alignment)
        int nb = 32 * wv + ln;
        #pragma unroll
        for (int mi = 0; mi < 2; ++mi)
            #pragma unroll
            for (int r = 0; r < 16; ++r) {
                int o = 32 * mi + (r & 3) + 8 * (r >> 2) + 4 * ls;
                sm[nb * 72 + o] = f2bf(fmaxf(acc[mi][r] + b2[o], 0.f));
            }
    }
    __syncthreads();
    {
        int n = tid >> 1, half = tid & 1;
        u16* dst = y2t + ((size_t)b * P2 + 4 + t0 + n) * 64 + half * 32;
        const u16* src = sm + n * 72 + half * 32;
        #pragma unroll
        for (int q = 0; q < 4; ++q)
            *(u16x8*)(dst + q * 8) = *(const u16x8*)(src + q * 8);
    }
}

// ---------------- conv3 MFMA + mean-pool: y2t -> pooled sums (B,128)
// block: 4 waves, M=128, N=128 t; wave = 64m x 64n. K = 9 shifts x 2 parts x 64 i.
__global__ __launch_bounds__(256) void conv3_pool_k(const u16* __restrict__ y2t,
                                                    const u16* __restrict__ a3,
                                                    const float* __restrict__ b3,
                                                    float* __restrict__ pooled) {
    __shared__ u16 sm[28224];              // B: 264 x 72 | A(at 19008): 128 x 72
    const int tid = threadIdx.x;
    const int b = blockIdx.y;
    const int t0 = blockIdx.x * 128;
    const int lane = tid & 63, wv = tid >> 6;
    const int ls = lane >> 5, ln = lane & 31;
    const int mh = wv & 1, nh = wv >> 1;

    const u16* y2b = y2t + (size_t)b * P2 * 64;
    #pragma unroll
    for (int it = 0; it < 9; ++it) {        // stage B window: 2112 granules (zero-fill OOB)
        int g = tid + it * 256;
        if (g < 2112) {
            int r = g >> 3, c8 = g & 7;
            int gr = 2 * t0 + r;
            u16x8 v;
            #pragma unroll
            for (int q = 0; q < 8; ++q) v[q] = 0;
            if (gr < P2) v = *(const u16x8*)(y2b + (size_t)gr * 64 + c8 * 8);
            *(u16x8*)(sm + r * 72 + c8 * 8) = v;
        }
    }
    #pragma unroll
    for (int it = 0; it < 4; ++it) {        // stage A chunk c=0
        int g = tid + it * 256;
        u16x8 v = *(const u16x8*)(a3 + g * 8);
        *(u16x8*)(sm + 19008 + (g >> 3) * 72 + (g & 7) * 8) = v;
    }
    __syncthreads();

    f32x16 acc[2][2];
    #pragma unroll
    for (int mi = 0; mi < 2; ++mi)
        #pragma unroll
        for (int ni = 0; ni < 2; ++ni)
            #pragma unroll
            for (int q = 0; q < 16; ++q) acc[mi][ni][q] = 0.f;

    bf16x8 bf[2][4];
    for (int c = 0;;) {
        int kk = c >> 1, part = c & 1;
        if (part == 0) {
            #pragma unroll
            for (int ni = 0; ni < 2; ++ni)
                #pragma unroll
                for (int step = 0; step < 4; ++step)
                    bf[ni][step] = *(const bf16x8*)(sm + (2 * (64 * nh + 32 * ni + ln) + kk) * 72 + (2 * step + ls) * 8);
        }
        (void)part;
        #pragma unroll
        for (int step = 0; step < 4; ++step)
            #pragma unroll
            for (int mi = 0; mi < 2; ++mi) {
                bf16x8 af = *(const bf16x8*)(sm + 19008 + (64 * mh + mi * 32 + ln) * 72 + (2 * step + ls) * 8);
                #pragma unroll
                for (int ni = 0; ni < 2; ++ni)
                    acc[mi][ni] = __builtin_amdgcn_mfma_f32_32x32x16_bf16(af, bf[ni][step], acc[mi][ni], 0, 0, 0);
            }
        if (++c == 18) break;
        __syncthreads();
        #pragma unroll
        for (int it = 0; it < 4; ++it) {
            int g = tid + it * 256;
            u16x8 v = *(const u16x8*)(a3 + (size_t)c * 8192 + g * 8);
            *(u16x8*)(sm + 19008 + (g >> 3) * 72 + (g & 7) * 8) = v;
        }
        __syncthreads();
    }

    // epilogue: bias+relu, mask t>=8000, col-partials -> LDS matrix reduce -> atomics
    float loc[32];
    #pragma unroll
    for (int mi = 0; mi < 2; ++mi)
        #pragma unroll
        for (int r = 0; r < 16; ++r) {
            int o = 64 * mh + 32 * mi + (r & 3) + 8 * (r >> 2) + 4 * ls;
            float bias = b3[o];
            float s = 0.f;
            #pragma unroll
            for (int ni = 0; ni < 2; ++ni) {
                int t = t0 + 64 * nh + 32 * ni + ln;
                float v = fmaxf(acc[mi][ni][r] + bias, 0.f);
                s += (t < T3) ? v : 0.f;
            }
            loc[mi * 16 + r] = s;
        }
    __syncthreads();
    float* smf = (float*)sm;               // [2 nh][128 o][32 ln] = 32 KB
    #pragma unroll
    for (int mi = 0; mi < 2; ++mi)
        #pragma unroll
        for (int r = 0; r < 16; ++r) {
            int o = 64 * mh + 32 * mi + (r & 3) + 8 * (r >> 2) + 4 * ls;
            smf[nh * 4096 + o * 32 + ln] = loc[mi * 16 + r];
        }
    __syncthreads();
    if (tid < 128) {
        int o = tid;
        float s = 0.f;
        #pragma unroll
        for (int j = 0; j < 32; ++j) {
            int col = (j + o) & 31;        // rotate to avoid bank conflicts
            s += smf[o * 32 + col] + smf[4096 + o * 32 + col];
        }
        atomicAdd(&pooled[b * 128 + o], s);
    }
}

// ---------------- linear head
__global__ __launch_bounds__(128) void feats_k(const float* __restrict__ pooled,
                                               const float* __restrict__ wl,
                                               const float* __restrict__ bl,
                                               float* __restrict__ amps,
                                               float* __restrict__ nmag) {
    int b = blockIdx.x;
    int o = threadIdx.x;
    __shared__ float pl[128];
    __shared__ float sh[128];
    pl[o] = pooled[b * 128 + o] * (1.0f / 8000.0f);
    __syncthreads();
    float acc = bl[o];
    #pragma unroll 8
    for (int i = 0; i < 128; ++i) acc = fmaf(pl[i], wl[o * 128 + i], acc);
    sh[o] = (o < 64) ? fmaxf(acc, 0.f) : 0.f;
    __syncthreads();
    for (int s = 64; s > 0; s >>= 1) {
        if (o < s) sh[o] += sh[o + s];
        __syncthreads();
    }
    float denom = sh[0] + 1e-6f;
    if (o < 64) amps[b * 64 + o] = fmaxf(acc, 0.f) / denom;
    else        nmag[b * 64 + (o - 64)] = acc;
}

// ---------------- synthesis
__global__ __launch_bounds__(256) void synth_k(const float* __restrict__ f0,
                                               const float* __restrict__ wn,
                                               const float* __restrict__ amps,
                                               const float* __restrict__ nmag,
                                               float* __restrict__ out) {
    int t = blockIdx.x * 256 + threadIdx.x;
    int b = blockIdx.y;
    __shared__ float sa[64];
    if (threadIdx.x < 64) sa[threadIdx.x] = amps[b * 64 + threadIdx.x];
    __syncthreads();
    float f0v = f0[(size_t)b * T0 + t];
    double u = (double)f0v * ((double)t * (4.0 / 63999.0));
    float uf = (float)(u - floor(u));
    float acc = 0.f;
    #pragma unroll
    for (int h = 1; h <= 64; ++h) {
        float x = uf * (float)h;
        x = x - floorf(x);
        acc = fmaf(sa[h - 1], __builtin_amdgcn_sinf(x), acc);
    }
    float nm = nmag[b * 64 + (t / 1000)];
    out[(size_t)b * T0 + t] = acc + wn[(size_t)b * T0 + t] * nm;
}

extern "C" void kernel_launch(void* const* d_in, const int* in_sizes, int n_in,
                              void* d_out, int out_size, void* d_ws, size_t ws_size,
                              hipStream_t stream) {
    const float* audio = (const float*)d_in[0];
    const float* f0    = (const float*)d_in[1];
    const float* wn    = (const float*)d_in[2];
    const float* w1    = (const float*)d_in[3];
    const float* b1    = (const float*)d_in[4];
    const float* w2    = (const float*)d_in[5];
    const float* b2    = (const float*)d_in[6];
    const float* w3    = (const float*)d_in[7];
    const float* b3    = (const float*)d_in[8];
    const float* wl    = (const float*)d_in[9];
    const float* bl    = (const float*)d_in[10];
    float* out = (float*)d_out;

    char* ws = (char*)d_ws;
    float* pooled = (float*)(ws);                       // 2048 f32
    float* amps   = (float*)(ws + 8192);                // 1024 f32
    float* nmag   = (float*)(ws + 12288);               // 1024 f32
    u16* y1t = (u16*)(ws + 16384);                      // 16*32008*32
    u16* y2t = (u16*)(ws + 16384 + 32776192ull);        // 16*16008*64
    u16* a2  = (u16*)(ws + 16384 + 32776192ull + 32784384ull);
    u16* a3  = (u16*)(ws + 16384 + 32776192ull + 32784384ull + 73728ull);

    hipMemsetAsync(pooled, 0, BATCH * 128 * sizeof(float), stream);

    prep_w_k<<<720, 256, 0, stream>>>(w2, w3, a2, a3);
    conv1_k<<<dim3(126, BATCH), 256, 0, stream>>>(audio, w1, b1, y1t);
    pad_y2_k<<<4, 256, 0, stream>>>(y2t);
    conv2_k<<<dim3(125, BATCH), 256, 0, stream>>>(y1t, a2, b2, y2t);
    conv3_pool_k<<<dim3(63, BATCH), 256, 0, stream>>>(y2t, a3, b3, pooled);
    feats_k<<<dim3(BATCH), 128, 0, stream>>>(pooled, wl, bl, amps, nmag);
    synth_k<<<dim3(T0 / 256, BATCH), 256, 0, stream>>>(f0, wn, amps, nmag, out);
}

// Round 4
// 176.136 us; speedup vs baseline: 3.2964x; 1.0394x over previous
//
#include <hip/hip_runtime.h>
#include <hip/hip_bf16.h>
#include <math.h>

typedef unsigned short u16;
typedef __bf16 bf16x8 __attribute__((ext_vector_type(8)));
typedef float  f32x16 __attribute__((ext_vector_type(16)));
typedef u16    u16x8  __attribute__((ext_vector_type(8)));

#define BATCH 16
#define T0 64000
#define T1 32000
#define T2 16000
#define T3 8000
#define P1 32008   // padded rows of y1t (4 zero rows each side)
#define P2 16008   // padded rows of y2t

static __device__ __forceinline__ u16 f2bf(float f) {
    __hip_bfloat16 h = __float2bfloat16(f);
    return *reinterpret_cast<u16*>(&h);
}
static __device__ __forceinline__ float bf2f(u16 u) {
    __hip_bfloat16 h;
    *reinterpret_cast<u16*>(&h) = u;
    return __bfloat162float(h);
}

// ---------------- weight prep (transposed for coalesced A-frag global reads)
// a2t[c][g][o][j]: c=kk*2+part (18), g=0..3 (i-granule), o=0..63, j=0..7 (i=8g+j)
// a3t[c][g][o][j]: c=kk*2+part (18), g=0..7,              o=0..127, j=0..7
__global__ __launch_bounds__(256) void prep_w_k(const float* __restrict__ w2,
                                                const float* __restrict__ w3,
                                                u16* __restrict__ a2t,
                                                u16* __restrict__ a3t) {
    int idx = blockIdx.x * 256 + threadIdx.x;
    if (idx < 36864) {
        int j = idx & 7, o = (idx >> 3) & 63, g = (idx >> 9) & 3, c = idx >> 11;
        int kk = c >> 1, part = c & 1, i = g * 8 + j;
        float v = w2[(o * 32 + i) * 9 + kk];
        u16 hv = f2bf(v);
        if (part) hv = f2bf(v - bf2f(hv));
        a2t[idx] = hv;
    } else if (idx < 36864 + 147456) {
        int jdx = idx - 36864;
        int j = jdx & 7, o = (jdx >> 3) & 127, g = (jdx >> 10) & 7, c = jdx >> 13;
        int kk = c >> 1, part = c & 1, i = g * 8 + j;
        float v = w3[(o * 64 + i) * 9 + kk];
        u16 hv = f2bf(v);
        if (part) hv = f2bf(v - bf2f(hv));
        a3t[jdx] = hv;
    }
}

// ---------------- conv1: audio (B,64000) -> y1t bf16 [b][P1 rows][32 ch], zero pad rows
__global__ __launch_bounds__(256) void conv1_k(const float* __restrict__ audio,
                                               const float* __restrict__ w1,
                                               const float* __restrict__ b1,
                                               u16* __restrict__ y1t) {
    int p = blockIdx.x * 256 + threadIdx.x;
    if (p >= P1) return;
    int b = blockIdx.y;
    u16* dst = y1t + ((size_t)b * P1 + p) * 32;
    int t = p - 4;
    if (t < 0 || t >= T1) {
        u16x8 z;
        #pragma unroll
        for (int q = 0; q < 8; ++q) z[q] = 0;
        #pragma unroll
        for (int q = 0; q < 4; ++q) *(u16x8*)(dst + q * 8) = z;
        return;
    }
    const float* ar = audio + (size_t)b * T0;
    float x[9];
    #pragma unroll
    for (int k = 0; k < 9; ++k) {
        int idx = 2 * t + k - 4;
        x[k] = (idx >= 0 && idx < T0) ? ar[idx] : 0.f;
    }
    #pragma unroll
    for (int q = 0; q < 4; ++q) {
        u16x8 v;
        #pragma unroll
        for (int j = 0; j < 8; ++j) {
            int c = q * 8 + j;
            float acc = b1[c];
            #pragma unroll
            for (int k = 0; k < 9; ++k) acc = fmaf(x[k], w1[c * 9 + k], acc);
            v[j] = f2bf(fmaxf(acc, 0.f));
        }
        *(u16x8*)(dst + q * 8) = v;
    }
}

// ---------------- zero pad rows of y2t (rows 0..3 and 16004..16007)
__global__ __launch_bounds__(256) void pad_y2_k(u16* __restrict__ y2t) {
    int g = blockIdx.x * 256 + threadIdx.x;
    if (g >= 1024) return;
    int b = g >> 6, rem = g & 63;
    int row8 = rem >> 3, c8 = rem & 7;
    int p = (row8 < 4) ? row8 : (16000 + row8);
    u16x8 z;
    #pragma unroll
    for (int q = 0; q < 8; ++q) z[q] = 0;
    *(u16x8*)(y2t + ((size_t)b * P2 + p) * 64 + c8 * 8) = z;
}

// ---------------- conv2 MFMA: y1t -> y2t bf16 [b][P2][64]
// block 256 thr = 4 waves (nh=0..3), M=64 full, N=512 (wave: 64m x 128n, mi=2 ni=4)
// B in LDS (xor-swizzled, parity-packed pair rows); A frags read直接 from global (L1/L2).
__global__ __launch_bounds__(256, 2) void conv2_k(const u16* __restrict__ y1t,
                                                  const u16* __restrict__ a2t,
                                                  const float* __restrict__ b2,
                                                  u16* __restrict__ y2t) {
    __shared__ u16 sm[36864];              // B: 516 pair-rows x 128B = 66048B; epi: 512x72x2 = 73728B
    const int tid = threadIdx.x;
    const int b = blockIdx.y;
    const int t0 = blockIdx.x * 512;
    const int lane = tid & 63, wv = tid >> 6;
    const int ls = lane >> 5, ln = lane & 31;
    const int nbase = 128 * wv;

    // stage B window: rows 2*t0 .. 2*t0+1031 (32ch x 64B), 4128 granules of 16B
    {
        const u16* y1b = y1t + (size_t)b * P1 * 32;
        int rbase = 2 * t0;
        #pragma unroll
        for (int it = 0; it < 17; ++it) {
            int g = tid + it * 256;
            if (g < 4128) {
                int row = g >> 2, gg = g & 3;
                int grow = rbase + row;
                u16x8 v;
                #pragma unroll
                for (int q = 0; q < 8; ++q) v[q] = 0;
                if (grow < P1) v = *(const u16x8*)(y1b + (size_t)grow * 32 + gg * 8);
                int rr = row >> 1, pp = row & 1;
                int slot = (pp * 4 + gg) ^ (rr & 7);
                *(u16x8*)(sm + rr * 64 + slot * 8) = v;
            }
        }
    }
    __syncthreads();

    f32x16 acc[2][4];
    #pragma unroll
    for (int mi = 0; mi < 2; ++mi)
        #pragma unroll
        for (int ni = 0; ni < 4; ++ni)
            #pragma unroll
            for (int q = 0; q < 16; ++q) acc[mi][ni][q] = 0.f;

    const int o8_0 = ln * 8, o8_1 = (32 + ln) * 8;
    bf16x8 bf[4][2];
    for (int c = 0; c < 18; ++c) {
        int kk = c >> 1;
        const u16* ap = a2t + (size_t)c * 2048;
        if ((c & 1) == 0) {
            int p = kk & 1, kh = kk >> 1;
            #pragma unroll
            for (int ni = 0; ni < 4; ++ni) {
                int rr = nbase + 32 * ni + ln + kh;
                #pragma unroll
                for (int step = 0; step < 2; ++step) {
                    int slot = (p * 4 + 2 * step + ls) ^ (rr & 7);
                    bf[ni][step] = *(const bf16x8*)(sm + rr * 64 + slot * 8);
                }
            }
        }
        #pragma unroll
        for (int step = 0; step < 2; ++step) {
            bf16x8 af0 = *(const bf16x8*)(ap + (2 * step + ls) * 512 + o8_0);
            bf16x8 af1 = *(const bf16x8*)(ap + (2 * step + ls) * 512 + o8_1);
            #pragma unroll
            for (int ni = 0; ni < 4; ++ni) {
                acc[0][ni] = __builtin_amdgcn_mfma_f32_32x32x16_bf16(af0, bf[ni][step], acc[0][ni], 0, 0, 0);
                acc[1][ni] = __builtin_amdgcn_mfma_f32_32x32x16_bf16(af1, bf[ni][step], acc[1][ni], 0, 0, 0);
            }
        }
    }
    __syncthreads();
    // epilogue: bias+relu -> LDS [t][o] (72-u16 rows), then coalesced store
    #pragma unroll
    for (int mi = 0; mi < 2; ++mi)
        #pragma unroll
        for (int r = 0; r < 16; ++r) {
            int o = 32 * mi + (r & 3) + 8 * (r >> 2) + 4 * ls;
            float bias = b2[o];
            #pragma unroll
            for (int ni = 0; ni < 4; ++ni) {
                int tl = nbase + 32 * ni + ln;
                sm[tl * 72 + o] = f2bf(fmaxf(acc[mi][ni][r] + bias, 0.f));
            }
        }
    __syncthreads();
    #pragma unroll
    for (int it = 0; it < 16; ++it) {
        int g = tid + it * 256;                 // 4096 granules
        int row = g >> 3, gg = g & 7;
        if (t0 + row < T2)
            *(u16x8*)(y2t + ((size_t)b * P2 + 4 + t0 + row) * 64 + gg * 8) =
                *(const u16x8*)(sm + row * 72 + gg * 8);
    }
}

// ---------------- conv3 MFMA + mean-pool: y2t -> pooled sums (B,128)
// block 256 thr = 4 waves (mh=wv&1, nh=wv>>1), M=128, N=256 (wave: 64m x 128n, mi=2 ni=4)
__global__ __launch_bounds__(256, 2) void conv3_pool_k(const u16* __restrict__ y2t,
                                                       const u16* __restrict__ a3t,
                                                       const float* __restrict__ b3,
                                                       float* __restrict__ pooled) {
    __shared__ u16 sm[33280];              // B: 520 rows x 128B = 66560B; epi floats 32KB
    const int tid = threadIdx.x;
    const int b = blockIdx.y;
    const int t0 = blockIdx.x * 256;
    const int lane = tid & 63, wv = tid >> 6;
    const int ls = lane >> 5, ln = lane & 31;
    const int mh = wv & 1, nh = wv >> 1;
    const int nbase = 128 * nh;

    // stage B window: rows 2*t0 .. 2*t0+519 (64ch x 128B), 4160 granules
    {
        const u16* y2b = y2t + (size_t)b * P2 * 64;
        int rbase = 2 * t0;
        #pragma unroll
        for (int it = 0; it < 17; ++it) {
            int g = tid + it * 256;
            if (g < 4160) {
                int row = g >> 3, gg = g & 7;
                int grow = rbase + row;
                u16x8 v;
                #pragma unroll
                for (int q = 0; q < 8; ++q) v[q] = 0;
                if (grow < P2) v = *(const u16x8*)(y2b + (size_t)grow * 64 + gg * 8);
                int slot = gg ^ ((row >> 1) & 7);
                *(u16x8*)(sm + row * 64 + slot * 8) = v;
            }
        }
    }
    __syncthreads();

    f32x16 acc[2][4];
    #pragma unroll
    for (int mi = 0; mi < 2; ++mi)
        #pragma unroll
        for (int ni = 0; ni < 4; ++ni)
            #pragma unroll
            for (int q = 0; q < 16; ++q) acc[mi][ni][q] = 0.f;

    const int o8_0 = (64 * mh + ln) * 8, o8_1 = (64 * mh + 32 + ln) * 8;
    bf16x8 bf[4][4];
    for (int c = 0; c < 18; ++c) {
        int kk = c >> 1;
        const u16* ap = a3t + (size_t)c * 8192;
        if ((c & 1) == 0) {
            int kh = kk >> 1;
            #pragma unroll
            for (int ni = 0; ni < 4; ++ni) {
                int nl = nbase + 32 * ni + ln;
                int row_local = 2 * nl + kk;
                int rh = nl + kh;                      // row_local>>1
                #pragma unroll
                for (int step = 0; step < 4; ++step) {
                    int slot = (2 * step + ls) ^ (rh & 7);
                    bf[ni][step] = *(const bf16x8*)(sm + row_local * 64 + slot * 8);
                }
            }
        }
        #pragma unroll
        for (int step = 0; step < 4; ++step) {
            bf16x8 af0 = *(const bf16x8*)(ap + (2 * step + ls) * 1024 + o8_0);
            bf16x8 af1 = *(const bf16x8*)(ap + (2 * step + ls) * 1024 + o8_1);
            #pragma unroll
            for (int ni = 0; ni < 4; ++ni) {
                acc[0][ni] = __builtin_amdgcn_mfma_f32_32x32x16_bf16(af0, bf[ni][step], acc[0][ni], 0, 0, 0);
                acc[1][ni] = __builtin_amdgcn_mfma_f32_32x32x16_bf16(af1, bf[ni][step], acc[1][ni], 0, 0, 0);
            }
        }
    }

    // epilogue: bias+relu, mask t>=8000, sum over ni -> LDS matrix reduce -> atomics
    float loc[32];
    #pragma unroll
    for (int mi = 0; mi < 2; ++mi)
        #pragma unroll
        for (int r = 0; r < 16; ++r) {
            int o = 64 * mh + 32 * mi + (r & 3) + 8 * (r >> 2) + 4 * ls;
            float bias = b3[o];
            float s = 0.f;
            #pragma unroll
            for (int ni = 0; ni < 4; ++ni) {
                int t = t0 + nbase + 32 * ni + ln;
                float v = fmaxf(acc[mi][ni][r] + bias, 0.f);
                s += (t < T3) ? v : 0.f;
            }
            loc[mi * 16 + r] = s;
        }
    __syncthreads();
    float* smf = (float*)sm;               // [2 nh][128 o][32 ln] = 32 KB
    #pragma unroll
    for (int mi = 0; mi < 2; ++mi)
        #pragma unroll
        for (int r = 0; r < 16; ++r) {
            int o = 64 * mh + 32 * mi + (r & 3) + 8 * (r >> 2) + 4 * ls;
            smf[nh * 4096 + o * 32 + ln] = loc[mi * 16 + r];
        }
    __syncthreads();
    if (tid < 128) {
        int o = tid;
        float s = 0.f;
        #pragma unroll
        for (int j = 0; j < 32; ++j) {
            int col = (j + o) & 31;
            s += smf[o * 32 + col] + smf[4096 + o * 32 + col];
        }
        atomicAdd(&pooled[b * 128 + o], s);
    }
}

// ---------------- linear head
__global__ __launch_bounds__(128) void feats_k(const float* __restrict__ pooled,
                                               const float* __restrict__ wl,
                                               const float* __restrict__ bl,
                                               float* __restrict__ amps,
                                               float* __restrict__ nmag) {
    int b = blockIdx.x;
    int o = threadIdx.x;
    __shared__ float pl[128];
    __shared__ float sh[128];
    pl[o] = pooled[b * 128 + o] * (1.0f / 8000.0f);
    __syncthreads();
    float acc = bl[o];
    #pragma unroll 8
    for (int i = 0; i < 128; ++i) acc = fmaf(pl[i], wl[o * 128 + i], acc);
    sh[o] = (o < 64) ? fmaxf(acc, 0.f) : 0.f;
    __syncthreads();
    for (int s = 64; s > 0; s >>= 1) {
        if (o < s) sh[o] += sh[o + s];
        __syncthreads();
    }
    float denom = sh[0] + 1e-6f;
    if (o < 64) amps[b * 64 + o] = fmaxf(acc, 0.f) / denom;
    else        nmag[b * 64 + (o - 64)] = acc;
}

// ---------------- synthesis
__global__ __launch_bounds__(256) void synth_k(const float* __restrict__ f0,
                                               const float* __restrict__ wn,
                                               const float* __restrict__ amps,
                                               const float* __restrict__ nmag,
                                               float* __restrict__ out) {
    int t = blockIdx.x * 256 + threadIdx.x;
    int b = blockIdx.y;
    __shared__ float sa[64];
    if (threadIdx.x < 64) sa[threadIdx.x] = amps[b * 64 + threadIdx.x];
    __syncthreads();
    float f0v = f0[(size_t)b * T0 + t];
    double u = (double)f0v * ((double)t * (4.0 / 63999.0));
    float uf = (float)(u - floor(u));
    float acc = 0.f;
    #pragma unroll
    for (int h = 1; h <= 64; ++h) {
        float x = uf * (float)h;
        x = x - floorf(x);
        acc = fmaf(sa[h - 1], __builtin_amdgcn_sinf(x), acc);
    }
    float nm = nmag[b * 64 + (t / 1000)];
    out[(size_t)b * T0 + t] = acc + wn[(size_t)b * T0 + t] * nm;
}

extern "C" void kernel_launch(void* const* d_in, const int* in_sizes, int n_in,
                              void* d_out, int out_size, void* d_ws, size_t ws_size,
                              hipStream_t stream) {
    const float* audio = (const float*)d_in[0];
    const float* f0    = (const float*)d_in[1];
    const float* wn    = (const float*)d_in[2];
    const float* w1    = (const float*)d_in[3];
    const float* b1    = (const float*)d_in[4];
    const float* w2    = (const float*)d_in[5];
    const float* b2    = (const float*)d_in[6];
    const float* w3    = (const float*)d_in[7];
    const float* b3    = (const float*)d_in[8];
    const float* wl    = (const float*)d_in[9];
    const float* bl    = (const float*)d_in[10];
    float* out = (float*)d_out;

    char* ws = (char*)d_ws;
    float* pooled = (float*)(ws);                       // 2048 f32
    float* amps   = (float*)(ws + 8192);
    float* nmag   = (float*)(ws + 12288);
    u16* y1t = (u16*)(ws + 16384);                      // 16*32008*32 u16
    u16* y2t = (u16*)(ws + 16384 + 32776192ull);        // 16*16008*64 u16
    u16* a2t = (u16*)(ws + 16384 + 32776192ull + 32784384ull);          // 36864 u16
    u16* a3t = (u16*)(ws + 16384 + 32776192ull + 32784384ull + 73728ull); // 147456 u16

    hipMemsetAsync(pooled, 0, BATCH * 128 * sizeof(float), stream);

    prep_w_k<<<720, 256, 0, stream>>>(w2, w3, a2t, a3t);
    conv1_k<<<dim3(126, BATCH), 256, 0, stream>>>(audio, w1, b1, y1t);
    pad_y2_k<<<4, 256, 0, stream>>>(y2t);
    conv2_k<<<dim3(32, BATCH), 256, 0, stream>>>(y1t, a2t, b2, y2t);
    conv3_pool_k<<<dim3(32, BATCH), 256, 0, stream>>>(y2t, a3t, b3, pooled);
    feats_k<<<dim3(BATCH), 128, 0, stream>>>(pooled, wl, bl, amps, nmag);
    synth_k<<<dim3(T0 / 256, BATCH), 256, 0, stream>>>(f0, wn, amps, nmag, out);
}